// Round 1
// baseline (83.716 us; speedup 1.0000x reference)
//
#include <hip/hip_runtime.h>

// EfficientRelativePositionalEncoding, MI355X (gfx950)
// B=2, N=2048, H=8, HID=16.  out[b][h][i][j], fp32, 268 MB.
//
// Folded math:
//   A[k][h]  = sum_m Wd2[k][m] * Wf[m][h]        (16x8)
//   Bm[k][h] = sum_m Wr2[k][m] * Wf[m+8][h]      (16x8)
//   c[h]     = bf[h] + sum_m bd2[m]*Wf[m][h] + sum_m br2[m]*Wf[m+8][h]
//   out = sum_k relu(dist*Wd1[k]+bd1[k])*A[k][h]
//       + sum_k relu(dir . Wr1[:,k]+br1[k])*Bm[k][h] + c[h]

#define BB 2
#define NN 2048
#define HH 8
#define HID 16

__global__ __launch_bounds__(256) void erpe_fold_weights(
    const float* __restrict__ Wd2, const float* __restrict__ bd2,
    const float* __restrict__ Wr2, const float* __restrict__ br2,
    const float* __restrict__ Wf,  const float* __restrict__ bf,
    float* __restrict__ ws)
{
    int t = threadIdx.x;
    if (t < 128) {
        int k = t >> 3, h = t & 7;
        float sa = 0.f, sb = 0.f;
        #pragma unroll
        for (int m = 0; m < HH; ++m) {
            sa += Wd2[k * HH + m] * Wf[m * HH + h];
            sb += Wr2[k * HH + m] * Wf[(m + HH) * HH + h];
        }
        ws[t]       = sa;   // A, flat [16][8]
        ws[128 + t] = sb;   // Bm, flat [16][8]
    } else if (t < 136) {
        int h = t - 128;
        float s = bf[h];
        #pragma unroll
        for (int m = 0; m < HH; ++m)
            s += bd2[m] * Wf[m * HH + h] + br2[m] * Wf[(m + HH) * HH + h];
        ws[256 + h] = s;    // c[8]
    }
}

// Each block: one (b, i, j-chunk of 1024). 256 threads x 4 j each.
// grid.x = BB * NN * 2 = 8192
__global__ __launch_bounds__(256) void erpe_main(
    const float* __restrict__ xyz,
    const float* __restrict__ Wd1, const float* __restrict__ bd1,
    const float* __restrict__ Wr1, const float* __restrict__ br1,
    const float* __restrict__ ws,
    float* __restrict__ out)
{
    __shared__ __align__(16) float sA[16][8];
    __shared__ __align__(16) float sB[16][8];
    __shared__ float sc[8];
    __shared__ float sWd1[16], sbd1[16], sbr1[16];
    __shared__ float sWr1[3][16];

    const int t = threadIdx.x;
    if (t < 128)       ((float*)sA)[t]       = ws[t];
    else               ((float*)sB)[t - 128] = ws[t];
    if (t < 8)         sc[t]   = ws[256 + t];
    if (t < 16)        { sWd1[t] = Wd1[t]; sbd1[t] = bd1[t]; sbr1[t] = br1[t]; }
    if (t >= 64 && t < 112) ((float*)sWr1)[t - 64] = Wr1[t - 64];
    __syncthreads();

    const int blk = blockIdx.x;
    const int jc  = blk & 1;
    const int i   = (blk >> 1) & (NN - 1);
    const int b   = blk >> 12;           // / (NN*2)

    const float* xb = xyz + (size_t)b * NN * 3;
    const float xi = xb[i * 3 + 0];
    const float yi = xb[i * 3 + 1];
    const float zi = xb[i * 3 + 2];

    const int j0 = jc * 1024 + t * 4;
    // 12 contiguous floats: xyz[j0..j0+3], 16B-aligned (j0 % 4 == 0)
    const float4* pj = reinterpret_cast<const float4*>(xb + (size_t)j0 * 3);
    const float4 q0 = pj[0], q1 = pj[1], q2 = pj[2];

    float px[4] = { q0.x, q0.w, q1.z, q2.y };
    float py[4] = { q0.y, q1.x, q1.w, q2.z };
    float pz[4] = { q0.z, q1.y, q2.x, q2.w };

    float dist[4], dirx[4], diry[4], dirz[4];
    #pragma unroll
    for (int jj = 0; jj < 4; ++jj) {
        const float dx = px[jj] - xi;
        const float dy = py[jj] - yi;
        const float dz = pz[jj] - zi;
        const float d  = sqrtf(dx * dx + dy * dy + dz * dz);
        const float inv = 1.0f / (d + 1e-7f);
        dist[jj] = d;
        dirx[jj] = dx * inv;
        diry[jj] = dy * inv;
        dirz[jj] = dz * inv;
    }

    float acc[4][8];
    #pragma unroll
    for (int jj = 0; jj < 4; ++jj)
        #pragma unroll
        for (int h = 0; h < 8; ++h)
            acc[jj][h] = sc[h];

    #pragma unroll
    for (int k = 0; k < 16; ++k) {
        const float wd = sWd1[k], bd = sbd1[k];
        const float w0 = sWr1[0][k], w1 = sWr1[1][k], w2 = sWr1[2][k];
        const float br = sbr1[k];
        const float4 a0 = *reinterpret_cast<const float4*>(&sA[k][0]);
        const float4 a1 = *reinterpret_cast<const float4*>(&sA[k][4]);
        const float4 b0 = *reinterpret_cast<const float4*>(&sB[k][0]);
        const float4 b1 = *reinterpret_cast<const float4*>(&sB[k][4]);
        #pragma unroll
        for (int jj = 0; jj < 4; ++jj) {
            const float td = fmaxf(fmaf(dist[jj], wd, bd), 0.f);
            const float tr = fmaxf(
                fmaf(dirx[jj], w0, fmaf(diry[jj], w1, fmaf(dirz[jj], w2, br))),
                0.f);
            acc[jj][0] = fmaf(td, a0.x, fmaf(tr, b0.x, acc[jj][0]));
            acc[jj][1] = fmaf(td, a0.y, fmaf(tr, b0.y, acc[jj][1]));
            acc[jj][2] = fmaf(td, a0.z, fmaf(tr, b0.z, acc[jj][2]));
            acc[jj][3] = fmaf(td, a0.w, fmaf(tr, b0.w, acc[jj][3]));
            acc[jj][4] = fmaf(td, a1.x, fmaf(tr, b1.x, acc[jj][4]));
            acc[jj][5] = fmaf(td, a1.y, fmaf(tr, b1.y, acc[jj][5]));
            acc[jj][6] = fmaf(td, a1.z, fmaf(tr, b1.z, acc[jj][6]));
            acc[jj][7] = fmaf(td, a1.w, fmaf(tr, b1.w, acc[jj][7]));
        }
    }

    float* ob = out + ((size_t)b * HH) * (size_t)NN * NN + (size_t)i * NN + j0;
    #pragma unroll
    for (int h = 0; h < 8; ++h) {
        float4 v = make_float4(acc[0][h], acc[1][h], acc[2][h], acc[3][h]);
        *reinterpret_cast<float4*>(ob + (size_t)h * NN * NN) = v;
    }
}

extern "C" void kernel_launch(void* const* d_in, const int* in_sizes, int n_in,
                              void* d_out, int out_size, void* d_ws, size_t ws_size,
                              hipStream_t stream) {
    const float* xyz = (const float*)d_in[0];
    const float* Wd1 = (const float*)d_in[1];
    const float* bd1 = (const float*)d_in[2];
    const float* Wd2 = (const float*)d_in[3];
    const float* bd2 = (const float*)d_in[4];
    const float* Wr1 = (const float*)d_in[5];
    const float* br1 = (const float*)d_in[6];
    const float* Wr2 = (const float*)d_in[7];
    const float* br2 = (const float*)d_in[8];
    const float* Wf  = (const float*)d_in[9];
    const float* bf  = (const float*)d_in[10];
    float* out = (float*)d_out;
    float* ws  = (float*)d_ws;

    erpe_fold_weights<<<1, 256, 0, stream>>>(Wd2, bd2, Wr2, br2, Wf, bf, ws);
    erpe_main<<<BB * NN * 2, 256, 0, stream>>>(xyz, Wd1, bd1, Wr1, br1, ws, out);
}

// Round 2
// 66.579 us; speedup vs baseline: 1.2574x; 1.2574x over previous
//
#include <hip/hip_runtime.h>

// EfficientRelativePositionalEncoding, MI355X (gfx950)
// B=2, N=2048, H=8, HID=16.  out[b][h][i][j], fp32, 268 MB write-bound.
//
// Folded math (fold kernel, unchanged from R1):
//   Afold[k][h] = sum_m Wd2[k][m] * Wf[m][h]        (16x8)   ws[0..127]
//   Bfold[k][h] = sum_m Wr2[k][m] * Wf[m+8][h]      (16x8)   ws[128..255]
//   c[h]        = bf[h] + bd2@Wf[0:8] + br2@Wf[8:16]         ws[256..263]
//
// Main kernel: the 2x(16x8) matvec per pair goes to the matrix pipe:
//   D = Wc^T (32x32, rows=h pad) . F (K=32 features x 32 pairs)
//   via two chained mfma_f32_32x32x16_f16 (K-half 1: td feats, half 2: tr).
// A and B frags use the SAME (lane-group, elem)->k convention, so any
// bijective HW k-permutation cancels in the dot product.
// C/D layout (HW-verified): col = lane&31, row = (reg&3)+8*(reg>>2)+4*(lane>>5)
//   -> regs 0..3 hold h = reg + 4*(lane>>5), cols = pairs.
// LDS transpose [64 j][10 pad] -> 256B-contiguous stores per h-plane.

#define BB 2
#define NN 2048
#define HH 8

typedef _Float16 f16x8 __attribute__((ext_vector_type(8)));
typedef float    f32x16 __attribute__((ext_vector_type(16)));

__global__ __launch_bounds__(256) void erpe_fold_weights(
    const float* __restrict__ Wd2, const float* __restrict__ bd2,
    const float* __restrict__ Wr2, const float* __restrict__ br2,
    const float* __restrict__ Wf,  const float* __restrict__ bf,
    float* __restrict__ ws)
{
    int t = threadIdx.x;
    if (t < 128) {
        int k = t >> 3, h = t & 7;
        float sa = 0.f, sb = 0.f;
        #pragma unroll
        for (int m = 0; m < HH; ++m) {
            sa += Wd2[k * HH + m] * Wf[m * HH + h];
            sb += Wr2[k * HH + m] * Wf[(m + HH) * HH + h];
        }
        ws[t]       = sa;   // Afold, flat [16][8]
        ws[128 + t] = sb;   // Bfold, flat [16][8]
    } else if (t < 136) {
        int h = t - 128;
        float s = bf[h];
        #pragma unroll
        for (int m = 0; m < HH; ++m)
            s += bd2[m] * Wf[m * HH + h] + br2[m] * Wf[(m + HH) * HH + h];
        ws[256 + h] = s;    // c[8]
    }
}

// grid = B*N blocks (4096), 256 threads = 4 waves; wave w owns j in [512w, 512w+512)
__global__ __launch_bounds__(256) void erpe_main(
    const float* __restrict__ xyz,
    const float* __restrict__ Wd1, const float* __restrict__ bd1,
    const float* __restrict__ Wr1, const float* __restrict__ br1,
    const float* __restrict__ ws,
    float* __restrict__ out)
{
    __shared__ float lds[4][64][10];   // [wave][j-local][h pad 10] = 10 KB

    const int tid  = threadIdx.x;
    const int wave = tid >> 6;
    const int lane = tid & 63;
    const int g    = lane >> 5;        // k-half group within frag
    const int jl   = lane & 31;        // pair-column within tile / h-row for A

    const int blk = blockIdx.x;
    const int i   = blk & (NN - 1);
    const int b   = blk >> 11;

    // ---- per-lane feature-layer weights: k = g*8 + e  (e = 0..7) ----
    const int kb = g * 8;
    float wd[8], bdv[8], w0[8], w1[8], w2[8], brv[8];
    #pragma unroll
    for (int e = 0; e < 8; ++e) {
        wd[e]  = Wd1[kb + e];
        bdv[e] = bd1[kb + e];
        w0[e]  = Wr1[0 * 16 + kb + e];
        w1[e]  = Wr1[1 * 16 + kb + e];
        w2[e]  = Wr1[2 * 16 + kb + e];
        brv[e] = br1[kb + e];
    }

    // ---- A fragments: row h = jl (zero for h>=8), elem e -> k = kb+e ----
    f16x8 A1, A2;
    #pragma unroll
    for (int e = 0; e < 8; ++e) {
        if (jl < 8) {
            A1[e] = (_Float16)ws[(kb + e) * 8 + jl];
            A2[e] = (_Float16)ws[128 + (kb + e) * 8 + jl];
        } else {
            A1[e] = (_Float16)0.f;
            A2[e] = (_Float16)0.f;
        }
    }
    float cb[4];
    #pragma unroll
    for (int r = 0; r < 4; ++r) cb[r] = ws[256 + g * 4 + r];

    const float* xb = xyz + (size_t)b * NN * 3;
    const float xi = xb[i * 3 + 0];
    const float yi = xb[i * 3 + 1];
    const float zi = xb[i * 3 + 2];

    float* ob = out + ((size_t)b * HH) * (size_t)NN * NN + (size_t)i * NN;
    float (*myl)[10] = lds[wave];

    const int jwave = wave * 512;

    for (int t2 = 0; t2 < 8; ++t2) {       // 8 groups of 64 j
        const int jg = jwave + t2 * 64;

        #pragma unroll
        for (int p = 0; p < 2; ++p) {      // two 32-pair MFMA tiles
            const int j = jg + p * 32 + jl;
            const float ax = xb[j * 3 + 0];
            const float ay = xb[j * 3 + 1];
            const float az = xb[j * 3 + 2];
            const float dx = ax - xi, dy = ay - yi, dz = az - zi;
            const float r2 = fmaf(dx, dx, fmaf(dy, dy, dz * dz));
            const float d  = __builtin_amdgcn_sqrtf(r2);
            const float inv = __builtin_amdgcn_rcpf(d + 1e-7f);
            const float ux = dx * inv, uy = dy * inv, uz = dz * inv;

            f16x8 Btd, Btr;
            #pragma unroll
            for (int e = 0; e < 8; ++e) {
                const float td = fmaxf(fmaf(d, wd[e], bdv[e]), 0.f);
                const float tr = fmaxf(
                    fmaf(ux, w0[e], fmaf(uy, w1[e], fmaf(uz, w2[e], brv[e]))),
                    0.f);
                Btd[e] = (_Float16)td;
                Btr[e] = (_Float16)tr;
            }

            f32x16 acc;
            #pragma unroll
            for (int q = 0; q < 16; ++q) acc[q] = 0.f;
            acc = __builtin_amdgcn_mfma_f32_32x32x16_f16(A1, Btd, acc, 0, 0, 0);
            acc = __builtin_amdgcn_mfma_f32_32x32x16_f16(A2, Btr, acc, 0, 0, 0);

            // regs 0..3: h = r + 4*g, col j -> LDS [j][h]
            float4 v = make_float4(acc[0] + cb[0], acc[1] + cb[1],
                                   acc[2] + cb[2], acc[3] + cb[3]);
            *reinterpret_cast<float4*>(&myl[p * 32 + jl][g * 4]) = v;
        }
        __syncthreads();

        // flush: 8 h-planes, 64 contiguous j per store instruction
        #pragma unroll
        for (int h = 0; h < 8; ++h) {
            const float val = myl[lane][h];
            ob[(size_t)h * NN * NN + jg + lane] = val;
        }
        __syncthreads();
    }
}

extern "C" void kernel_launch(void* const* d_in, const int* in_sizes, int n_in,
                              void* d_out, int out_size, void* d_ws, size_t ws_size,
                              hipStream_t stream) {
    const float* xyz = (const float*)d_in[0];
    const float* Wd1 = (const float*)d_in[1];
    const float* bd1 = (const float*)d_in[2];
    const float* Wd2 = (const float*)d_in[3];
    const float* bd2 = (const float*)d_in[4];
    const float* Wr1 = (const float*)d_in[5];
    const float* br1 = (const float*)d_in[6];
    const float* Wr2 = (const float*)d_in[7];
    const float* br2 = (const float*)d_in[8];
    const float* Wf  = (const float*)d_in[9];
    const float* bf  = (const float*)d_in[10];
    float* out = (float*)d_out;
    float* ws  = (float*)d_ws;

    erpe_fold_weights<<<1, 256, 0, stream>>>(Wd2, bd2, Wr2, br2, Wf, bf, ws);
    erpe_main<<<BB * NN, 256, 0, stream>>>(xyz, Wd1, bd1, Wr1, br1, ws, out);
}

// Round 3
// 57.974 us; speedup vs baseline: 1.4440x; 1.1484x over previous
//
#include <hip/hip_runtime.h>

// EfficientRelativePositionalEncoding, MI355X (gfx950)
// B=2, N=2048, H=8, HID=16.  out[b][h][i][j], fp32, 268 MB write-bound.
//
// Folded math (fold kernel):
//   Afold[k][h] = sum_m Wd2[k][m] * Wf[m][h]        (16x8)   ws[0..127]
//   Bfold[k][h] = sum_m Wr2[k][m] * Wf[m+8][h]      (16x8)   ws[128..255]
//   c[h]        = bf[h] + bd2@Wf[0:8] + br2@Wf[8:16]         ws[256..263]
//
// Main kernel: per 32-pair tile, D = Wc^T . F via two chained
// mfma_f32_32x32x16_f16 (K-half 1: dist feats, half 2: dir feats).
// A and B frags use the SAME (lane-group, elem)->k convention, so any
// bijective HW k-permutation cancels in the dot product.
// C/D layout (HW-verified): col = lane&31, row = (reg&3)+8*(reg>>2)+4*(lane>>5)
//   -> regs 0..3 hold h = reg + 4*(lane>>5), cols = pairs.
// Direct global stores: per reg r, lanes 0-31 write 128B contiguous in plane
// h=r, lanes 32-63 write 128B contiguous in plane h=r+4 -> two fully-written
// 128B segments per instruction. No LDS, no barriers: waves fully independent.
// Output bias c[h] is folded into the MFMA C-in (acc[0..3] init).

#define BB 2
#define NN 2048
#define HH 8

typedef _Float16 f16x8 __attribute__((ext_vector_type(8)));
typedef float    f32x16 __attribute__((ext_vector_type(16)));

__global__ __launch_bounds__(256) void erpe_fold_weights(
    const float* __restrict__ Wd2, const float* __restrict__ bd2,
    const float* __restrict__ Wr2, const float* __restrict__ br2,
    const float* __restrict__ Wf,  const float* __restrict__ bf,
    float* __restrict__ ws)
{
    int t = threadIdx.x;
    if (t < 128) {
        int k = t >> 3, h = t & 7;
        float sa = 0.f, sb = 0.f;
        #pragma unroll
        for (int m = 0; m < HH; ++m) {
            sa += Wd2[k * HH + m] * Wf[m * HH + h];
            sb += Wr2[k * HH + m] * Wf[(m + HH) * HH + h];
        }
        ws[t]       = sa;   // Afold, flat [16][8]
        ws[128 + t] = sb;   // Bfold, flat [16][8]
    } else if (t < 136) {
        int h = t - 128;
        float s = bf[h];
        #pragma unroll
        for (int m = 0; m < HH; ++m)
            s += bd2[m] * Wf[m * HH + h] + br2[m] * Wf[(m + HH) * HH + h];
        ws[256 + h] = s;    // c[8]
    }
}

// grid = B*N blocks (4096), 256 threads = 4 waves; wave w owns j in [512w, 512w+512)
__global__ __launch_bounds__(256) void erpe_main(
    const float* __restrict__ xyz,
    const float* __restrict__ Wd1, const float* __restrict__ bd1,
    const float* __restrict__ Wr1, const float* __restrict__ br1,
    const float* __restrict__ ws,
    float* __restrict__ out)
{
    const int tid  = threadIdx.x;
    const int wave = tid >> 6;
    const int lane = tid & 63;
    const int g    = lane >> 5;        // k-half group within frag
    const int jl   = lane & 31;        // pair-column within tile / h-row for A

    const int blk = blockIdx.x;
    const int i   = blk & (NN - 1);
    const int b   = blk >> 11;

    // ---- per-lane feature-layer weights: k = g*8 + e  (e = 0..7) ----
    const int kb = g * 8;
    float wd[8], bdv[8], w0[8], w1[8], w2[8], brv[8];
    #pragma unroll
    for (int e = 0; e < 8; ++e) {
        wd[e]  = Wd1[kb + e];
        bdv[e] = bd1[kb + e];
        w0[e]  = Wr1[0 * 16 + kb + e];
        w1[e]  = Wr1[1 * 16 + kb + e];
        w2[e]  = Wr1[2 * 16 + kb + e];
        brv[e] = br1[kb + e];
    }

    // ---- A fragments: row h = jl (zero for h>=8), elem e -> k = kb+e ----
    f16x8 A1, A2;
    #pragma unroll
    for (int e = 0; e < 8; ++e) {
        if (jl < 8) {
            A1[e] = (_Float16)ws[(kb + e) * 8 + jl];
            A2[e] = (_Float16)ws[128 + (kb + e) * 8 + jl];
        } else {
            A1[e] = (_Float16)0.f;
            A2[e] = (_Float16)0.f;
        }
    }
    // output bias for this lane's h rows (folded into MFMA C-in)
    float cb[4];
    #pragma unroll
    for (int r = 0; r < 4; ++r) cb[r] = ws[256 + g * 4 + r];

    const float* xb = xyz + (size_t)b * NN * 3;
    const float xi = xb[i * 3 + 0];
    const float yi = xb[i * 3 + 1];
    const float zi = xb[i * 3 + 2];

    float* ob = out + ((size_t)b * HH) * (size_t)NN * NN + (size_t)i * NN;
    const int jwave = wave * 512;

    for (int t2 = 0; t2 < 8; ++t2) {       // 8 groups of 64 j
        const int jg = jwave + t2 * 64;

        #pragma unroll
        for (int p = 0; p < 2; ++p) {      // two 32-pair MFMA tiles
            const int j = jg + p * 32 + jl;
            const float ax = xb[j * 3 + 0];
            const float ay = xb[j * 3 + 1];
            const float az = xb[j * 3 + 2];
            const float dx = ax - xi, dy = ay - yi, dz = az - zi;
            const float r2 = fmaf(dx, dx, fmaf(dy, dy, dz * dz));
            const float d  = __builtin_amdgcn_sqrtf(r2);
            const float inv = __builtin_amdgcn_rcpf(d + 1e-7f);
            const float ux = dx * inv, uy = dy * inv, uz = dz * inv;

            f16x8 Btd, Btr;
            #pragma unroll
            for (int e = 0; e < 8; ++e) {
                const float td = fmaxf(fmaf(d, wd[e], bdv[e]), 0.f);
                const float tr = fmaxf(
                    fmaf(ux, w0[e], fmaf(uy, w1[e], fmaf(uz, w2[e], brv[e]))),
                    0.f);
                Btd[e] = (_Float16)td;
                Btr[e] = (_Float16)tr;
            }

            f32x16 acc;
            #pragma unroll
            for (int q = 0; q < 16; ++q) acc[q] = (q < 4) ? cb[q] : 0.f;
            acc = __builtin_amdgcn_mfma_f32_32x32x16_f16(A1, Btd, acc, 0, 0, 0);
            acc = __builtin_amdgcn_mfma_f32_32x32x16_f16(A2, Btr, acc, 0, 0, 0);

            // direct store: reg r -> plane h = r + 4*g, col j
            #pragma unroll
            for (int r = 0; r < 4; ++r)
                ob[(size_t)(r + 4 * g) * NN * NN + j] = acc[r];
        }
    }
}

extern "C" void kernel_launch(void* const* d_in, const int* in_sizes, int n_in,
                              void* d_out, int out_size, void* d_ws, size_t ws_size,
                              hipStream_t stream) {
    const float* xyz = (const float*)d_in[0];
    const float* Wd1 = (const float*)d_in[1];
    const float* bd1 = (const float*)d_in[2];
    const float* Wd2 = (const float*)d_in[3];
    const float* bd2 = (const float*)d_in[4];
    const float* Wr1 = (const float*)d_in[5];
    const float* br1 = (const float*)d_in[6];
    const float* Wr2 = (const float*)d_in[7];
    const float* br2 = (const float*)d_in[8];
    const float* Wf  = (const float*)d_in[9];
    const float* bf  = (const float*)d_in[10];
    float* out = (float*)d_out;
    float* ws  = (float*)d_ws;

    erpe_fold_weights<<<1, 256, 0, stream>>>(Wd2, bd2, Wr2, br2, Wf, bf, ws);
    erpe_main<<<BB * NN, 256, 0, stream>>>(xyz, Wd1, bd1, Wr1, br1, ws, out);
}